// Round 1
// baseline (3469.963 us; speedup 1.0000x reference)
//
#include <hip/hip_runtime.h>
#include <hip/hip_bf16.h>
#include <math.h>

typedef float4 f4;

#define NEG_SLOPE 0.2f

__device__ __forceinline__ void atomicMaxF(float* addr, float v) {
    // works with init = 0xFFFFFFFF (acts as -inf for this ordering)
    if (v >= 0.0f) atomicMax((int*)addr, __float_as_int(v));
    else           atomicMin((unsigned int*)addr, __float_as_uint(v));
}

// ---- M[d][h] = sum_c We[d, h*C+c] * ae[h, c]   (M1: 16x4 from We1/ae1, M2 from We2/ae2)
__global__ void k_prep(const float* __restrict__ We1, const float* __restrict__ ae1,
                       const float* __restrict__ We2, const float* __restrict__ ae2,
                       float* __restrict__ M) {
    int t = threadIdx.x;                  // 128 threads
    if (t >= 128) return;
    int sel = t >> 6, i = t & 63, d = i >> 2, h = i & 3;
    const float* W  = sel ? We2 : We1;
    const float* ae = sel ? ae2 : ae1;
    int C = sel ? 8 : 32, ncol = sel ? 32 : 128;
    float s = 0.f;
    for (int c = 0; c < C; ++c) s += W[d * ncol + h * C + c] * ae[h * C + c];
    M[sel * 64 + d * 4 + h] = s;
}

// ---- per real edge: deg[dst]++, loopsum[dst][0:16] += ea[e]
__global__ void k_loopsum(const int* __restrict__ ei, const float* __restrict__ ea,
                          float* __restrict__ loopsum, int* __restrict__ deg, int E) {
    int e = blockIdx.x * 256 + threadIdx.x;
    if (e >= E) return;
    int d = ei[E + e];
    atomicAdd(&deg[d], 1);
    const f4* row = (const f4*)(ea + (size_t)e * 16);
    f4 a0 = row[0], a1 = row[1], a2 = row[2], a3 = row[3];
    float* ls = loopsum + (size_t)d * 16;
    unsafeAtomicAdd(ls + 0,  a0.x); unsafeAtomicAdd(ls + 1,  a0.y);
    unsafeAtomicAdd(ls + 2,  a0.z); unsafeAtomicAdd(ls + 3,  a0.w);
    unsafeAtomicAdd(ls + 4,  a1.x); unsafeAtomicAdd(ls + 5,  a1.y);
    unsafeAtomicAdd(ls + 6,  a1.z); unsafeAtomicAdd(ls + 7,  a1.w);
    unsafeAtomicAdd(ls + 8,  a2.x); unsafeAtomicAdd(ls + 9,  a2.y);
    unsafeAtomicAdd(ls + 10, a2.z); unsafeAtomicAdd(ls + 11, a2.w);
    unsafeAtomicAdd(ls + 12, a3.x); unsafeAtomicAdd(ls + 13, a3.y);
    unsafeAtomicAdd(ls + 14, a3.z); unsafeAtomicAdd(ls + 15, a3.w);
}

// ---- exclusive scan of deg -> offsets[0..N], cursor copy. One block of 1024.
__global__ void k_scan(const int* __restrict__ deg, int* __restrict__ offsets,
                       int* __restrict__ cursor, int N) {
    __shared__ int ts[1024];
    int t = threadIdx.x;
    int CH = (N + 1023) / 1024;
    int lo = t * CH, hi = min(lo + CH, N);
    int s = 0;
    for (int i = lo; i < hi; ++i) s += deg[i];
    ts[t] = s;
    __syncthreads();
    for (int off = 1; off < 1024; off <<= 1) {
        int v = (t >= off) ? ts[t - off] : 0;
        __syncthreads();
        ts[t] += v;
        __syncthreads();
    }
    int run = (t == 0) ? 0 : ts[t - 1];
    for (int i = lo; i < hi; ++i) { offsets[i] = run; cursor[i] = run; run += deg[i]; }
    if (t == 1023) offsets[N] = ts[1023];
}

// ---- fill CSR (by dst) with src node and edge id
__global__ void k_fill(const int* __restrict__ ei, int* __restrict__ cursor,
                       int* __restrict__ csr_src, int* __restrict__ csr_eid, int E) {
    int e = blockIdx.x * 256 + threadIdx.x;
    if (e >= E) return;
    int d = ei[E + e];
    int slot = atomicAdd(&cursor[d], 1);
    csr_src[slot] = ei[e];
    csr_eid[slot] = e;
}

// ---- simple LDS-tiled fp32 GEMM: Hout[N,NOUT] = X[N,128] @ W[128,NOUT]
template<int NOUT, int ROWS>
__global__ __launch_bounds__(256) void k_gemm(const float* __restrict__ X,
                                              const float* __restrict__ W,
                                              float* __restrict__ Hout, int N) {
    __shared__ __align__(16) float xs[ROWS][128];
    int row0 = blockIdx.x * ROWS;
    int tid = threadIdx.x;
    constexpr int NF4 = ROWS * 32;
    const f4* x4 = (const f4*)X;
    for (int i = tid; i < NF4; i += 256) {
        int r = i >> 5, k4 = i & 31;
        f4 v;
        if (row0 + r < N) v = x4[(size_t)(row0 + r) * 32 + k4];
        else { v.x = v.y = v.z = v.w = 0.f; }
        ((f4*)&xs[r][0])[k4] = v;
    }
    __syncthreads();
    constexpr int GRP = 256 / NOUT;
    constexpr int PR  = ROWS / GRP;
    int col = tid % NOUT, rg = tid / NOUT;
    float acc[PR];
#pragma unroll
    for (int r = 0; r < PR; ++r) acc[r] = 0.f;
    for (int k = 0; k < 128; ++k) {
        float w = W[k * NOUT + col];
#pragma unroll
        for (int r = 0; r < PR; ++r) acc[r] += xs[rg + r * GRP][k] * w;
    }
#pragma unroll
    for (int r = 0; r < PR; ++r) {
        int row = row0 + rg + r * GRP;
        if (row < N) Hout[(size_t)row * NOUT + col] = acc[r];
    }
}

// ---- per (node, head): al_src/al_dst from h
template<int C>
__global__ void k_al(const float* __restrict__ Hm, const float* __restrict__ as_,
                     const float* __restrict__ ad_, float* __restrict__ als,
                     float* __restrict__ ald, int N) {
    int idx = blockIdx.x * 256 + threadIdx.x;
    int n = idx >> 2, h = idx & 3;
    if (n >= N) return;
    constexpr int CH = C / 4;
    const float* hr = Hm + (size_t)n * C + h * CH;
    float a = 0.f, b = 0.f;
#pragma unroll
    for (int c = 0; c < CH; ++c) { float v = hr[c]; a += v * as_[h * CH + c]; b += v * ad_[h * CH + c]; }
    als[n * 4 + h] = a;
    ald[n * 4 + h] = b;
}

// ---- per edge (incl. self-loops): alpha_raw = leaky(al_src[src]+al_dst[dst]+ea.M), atomicMax amax[dst]
__global__ void k_alpha_raw(const int* __restrict__ ei, const float* __restrict__ ea,
                            const float* __restrict__ loopsum, const int* __restrict__ deg,
                            const float* __restrict__ Mbuf, int msel,
                            const float* __restrict__ als, const float* __restrict__ ald,
                            float* __restrict__ alpha, float* __restrict__ amax,
                            int E, int N) {
    __shared__ float Ms[64];
    if (threadIdx.x < 64) Ms[threadIdx.x] = Mbuf[msel * 64 + threadIdx.x];
    __syncthreads();
    int e = blockIdx.x * 256 + threadIdx.x;
    int Ef = E + N;
    if (e >= Ef) return;
    int sr, ds;
    float a[16];
    if (e < E) {
        sr = ei[e]; ds = ei[E + e];
        const f4* row = (const f4*)(ea + (size_t)e * 16);
        f4 r0 = row[0], r1 = row[1], r2 = row[2], r3 = row[3];
        a[0]=r0.x; a[1]=r0.y; a[2]=r0.z; a[3]=r0.w;
        a[4]=r1.x; a[5]=r1.y; a[6]=r1.z; a[7]=r1.w;
        a[8]=r2.x; a[9]=r2.y; a[10]=r2.z; a[11]=r2.w;
        a[12]=r3.x; a[13]=r3.y; a[14]=r3.z; a[15]=r3.w;
    } else {
        int n = e - E; sr = n; ds = n;
        float rdeg = 1.0f / fmaxf((float)deg[n], 1.0f);
        const f4* row = (const f4*)(loopsum + (size_t)n * 16);
        f4 r0 = row[0], r1 = row[1], r2 = row[2], r3 = row[3];
        a[0]=r0.x*rdeg; a[1]=r0.y*rdeg; a[2]=r0.z*rdeg; a[3]=r0.w*rdeg;
        a[4]=r1.x*rdeg; a[5]=r1.y*rdeg; a[6]=r1.z*rdeg; a[7]=r1.w*rdeg;
        a[8]=r2.x*rdeg; a[9]=r2.y*rdeg; a[10]=r2.z*rdeg; a[11]=r2.w*rdeg;
        a[12]=r3.x*rdeg; a[13]=r3.y*rdeg; a[14]=r3.z*rdeg; a[15]=r3.w*rdeg;
    }
    float ale0 = 0.f, ale1 = 0.f, ale2 = 0.f, ale3 = 0.f;
#pragma unroll
    for (int d = 0; d < 16; ++d) {
        float av = a[d];
        ale0 += av * Ms[d * 4 + 0]; ale1 += av * Ms[d * 4 + 1];
        ale2 += av * Ms[d * 4 + 2]; ale3 += av * Ms[d * 4 + 3];
    }
    f4 s4 = ((const f4*)als)[sr];
    f4 d4 = ((const f4*)ald)[ds];
    float v[4] = { s4.x + d4.x + ale0, s4.y + d4.y + ale1,
                   s4.z + d4.z + ale2, s4.w + d4.w + ale3 };
#pragma unroll
    for (int h = 0; h < 4; ++h) {
        float x = v[h];
        x = (x > 0.f) ? x : NEG_SLOPE * x;
        v[h] = x;
        atomicMaxF(&amax[ds * 4 + h], x);
    }
    f4 o; o.x = v[0]; o.y = v[1]; o.z = v[2]; o.w = v[3];
    ((f4*)alpha)[e] = o;
}

// ---- per edge: alpha = exp(alpha - amax[dst]); denom[dst] += alpha
__global__ void k_alpha_exp(const int* __restrict__ ei, float* __restrict__ alpha,
                            const float* __restrict__ amax, float* __restrict__ denom,
                            int E, int N) {
    int e = blockIdx.x * 256 + threadIdx.x;
    int Ef = E + N;
    if (e >= Ef) return;
    int ds = (e < E) ? ei[E + e] : (e - E);
    f4 al = ((const f4*)alpha)[e];
    f4 mx = ((const f4*)amax)[ds];
    f4 r;
    r.x = expf(al.x - mx.x); r.y = expf(al.y - mx.y);
    r.z = expf(al.z - mx.z); r.w = expf(al.w - mx.w);
    ((f4*)alpha)[e] = r;
    unsafeAtomicAdd(&denom[ds * 4 + 0], r.x);
    unsafeAtomicAdd(&denom[ds * 4 + 1], r.y);
    unsafeAtomicAdd(&denom[ds * 4 + 2], r.z);
    unsafeAtomicAdd(&denom[ds * 4 + 3], r.w);
}

// ---- wave-per-node aggregation: Out[n] = relu( sum_in alpha_norm * Hm[src] + bias )
template<int C>
__global__ __launch_bounds__(256) void k_agg(const float* __restrict__ Hm,
                                             const float* __restrict__ alpha,
                                             const float* __restrict__ denom,
                                             const int* __restrict__ offsets,
                                             const int* __restrict__ csr_src,
                                             const int* __restrict__ csr_eid,
                                             const float* __restrict__ bias,
                                             float* __restrict__ Out, int E, int N) {
    int n = (blockIdx.x * 256 + threadIdx.x) >> 6;
    int lane = threadIdx.x & 63;
    if (n >= N) return;
    int s0 = offsets[n], s1 = offsets[n + 1];
    if constexpr (C == 128) {
        int c0 = lane, c1 = lane + 64;
        int h0 = c0 >> 5, h1 = c1 >> 5;
        float rd0 = 1.f / (denom[n * 4 + h0] + 1e-16f);
        float rd1 = 1.f / (denom[n * 4 + h1] + 1e-16f);
        // self-loop
        float a0 = alpha[(size_t)(E + n) * 4 + h0] * rd0;
        float a1 = alpha[(size_t)(E + n) * 4 + h1] * rd1;
        const float* hn = Hm + (size_t)n * 128;
        float acc0 = a0 * hn[c0], acc1 = a1 * hn[c1];
        for (int s = s0; s < s1; ++s) {
            int sr = csr_src[s], eid = csr_eid[s];
            float b0 = alpha[(size_t)eid * 4 + h0] * rd0;
            float b1 = alpha[(size_t)eid * 4 + h1] * rd1;
            const float* hr = Hm + (size_t)sr * 128;
            acc0 += b0 * hr[c0];
            acc1 += b1 * hr[c1];
        }
        Out[(size_t)n * 128 + c0] = fmaxf(acc0 + bias[c0], 0.f);
        Out[(size_t)n * 128 + c1] = fmaxf(acc1 + bias[c1], 0.f);
    } else {
        int c = lane & 31, half = lane >> 5;
        int hd = c >> 3;
        float rd = 1.f / (denom[n * 4 + hd] + 1e-16f);
        float acc = 0.f;
        if (half == 0) acc = alpha[(size_t)(E + n) * 4 + hd] * rd * Hm[(size_t)n * 32 + c];
        for (int s = s0 + half; s < s1; s += 2) {
            int sr = csr_src[s], eid = csr_eid[s];
            acc += alpha[(size_t)eid * 4 + hd] * rd * Hm[(size_t)sr * 32 + c];
        }
        acc += __shfl_xor(acc, 32);
        if (half == 0) Out[(size_t)n * 32 + c] = fmaxf(acc + bias[c], 0.f);
    }
}

// ---- mean pool accumulation
__global__ void k_pool(const float* __restrict__ out2, const int* __restrict__ batch,
                       float* __restrict__ pooled, int* __restrict__ cnt, int N) {
    int idx = blockIdx.x * 256 + threadIdx.x;
    int n = idx >> 5, c = idx & 31;
    if (n >= N) return;
    int g = batch[n];
    unsafeAtomicAdd(&pooled[g * 32 + c], out2[(size_t)n * 32 + c]);
    if (c == 0) atomicAdd(&cnt[g], 1);
}

// ---- final: out[g,cls] = (pooled[g]/cnt[g]) @ Wfc + bfc
__global__ void k_final(const float* __restrict__ pooled, const int* __restrict__ cnt,
                        const float* __restrict__ Wfc, const float* __restrict__ bfc,
                        float* __restrict__ out) {
    int t = threadIdx.x;
    if (t >= 640) return;
    int g = t / 10, cls = t % 10;
    float rc = 1.f / fmaxf((float)cnt[g], 1.f);
    float acc = bfc[cls];
    for (int c = 0; c < 32; ++c) acc += pooled[g * 32 + c] * rc * Wfc[c * 10 + cls];
    out[g * 10 + cls] = acc;
}

extern "C" void kernel_launch(void* const* d_in, const int* in_sizes, int n_in,
                              void* d_out, int out_size, void* d_ws, size_t ws_size,
                              hipStream_t stream) {
    const float* x    = (const float*)d_in[0];
    const int*   ei   = (const int*)  d_in[1];
    const float* ea   = (const float*)d_in[2];
    const int*   batch= (const int*)  d_in[3];
    const float* W1   = (const float*)d_in[4];
    const float* as1  = (const float*)d_in[5];
    const float* ad1  = (const float*)d_in[6];
    const float* We1  = (const float*)d_in[7];
    const float* ae1  = (const float*)d_in[8];
    const float* b1   = (const float*)d_in[9];
    const float* W2   = (const float*)d_in[10];
    const float* as2  = (const float*)d_in[11];
    const float* ad2  = (const float*)d_in[12];
    const float* We2  = (const float*)d_in[13];
    const float* ae2  = (const float*)d_in[14];
    const float* b2   = (const float*)d_in[15];
    const float* Wfc  = (const float*)d_in[16];
    const float* bfc  = (const float*)d_in[17];
    float* out = (float*)d_out;

    const int N  = in_sizes[3];       // 50000
    const int E  = in_sizes[1] / 2;   // 1600000
    const int Ef = E + N;

    // workspace layout (~98 MB)
    char* w = (char*)d_ws;
    size_t off = 0;
    auto alloc = [&](size_t bytes) -> void* {
        void* p = w + off;
        off = (off + bytes + 255) & ~(size_t)255;
        return p;
    };
    int*   deg     = (int*)  alloc((size_t)N * 4);
    int*   offsets = (int*)  alloc((size_t)(N + 1) * 4);
    int*   cursor  = (int*)  alloc((size_t)N * 4);
    int*   csr_src = (int*)  alloc((size_t)E * 4);
    int*   csr_eid = (int*)  alloc((size_t)E * 4);
    float* loopsum = (float*)alloc((size_t)N * 16 * 4);
    float* Mbuf    = (float*)alloc(128 * 4);
    float* h1      = (float*)alloc((size_t)N * 128 * 4);
    float* out1    = (float*)alloc((size_t)N * 128 * 4);
    float* als     = (float*)alloc((size_t)N * 4 * 4);
    float* ald     = (float*)alloc((size_t)N * 4 * 4);
    float* alpha   = (float*)alloc((size_t)Ef * 4 * 4);
    float* amax    = (float*)alloc((size_t)N * 4 * 4);
    float* denom   = (float*)alloc((size_t)N * 4 * 4);
    int*   cnt     = (int*)  alloc(64 * 4);
    float* pooled  = (float*)alloc(64 * 32 * 4);
    float* h2   = h1;   // h1 dead after layer-1 aggregation
    float* out2 = out1; // out1 dead after layer-2 GEMM

    const int eb  = (E + 255) / 256;
    const int efb = (Ef + 255) / 256;

    hipMemsetAsync(deg,     0, (size_t)N * 4, stream);
    hipMemsetAsync(loopsum, 0, (size_t)N * 16 * 4, stream);
    hipMemsetAsync(cnt,     0, 64 * 4, stream);
    hipMemsetAsync(pooled,  0, 64 * 32 * 4, stream);

    k_prep<<<1, 128, 0, stream>>>(We1, ae1, We2, ae2, Mbuf);
    k_loopsum<<<eb, 256, 0, stream>>>(ei, ea, loopsum, deg, E);
    k_scan<<<1, 1024, 0, stream>>>(deg, offsets, cursor, N);
    k_fill<<<eb, 256, 0, stream>>>(ei, cursor, csr_src, csr_eid, E);

    // ---------- layer 1 ----------
    k_gemm<128, 16><<<(N + 15) / 16, 256, 0, stream>>>(x, W1, h1, N);
    k_al<128><<<(N * 4 + 255) / 256, 256, 0, stream>>>(h1, as1, ad1, als, ald, N);
    hipMemsetAsync(amax, 0xFF, (size_t)N * 16, stream);
    hipMemsetAsync(denom, 0,   (size_t)N * 16, stream);
    k_alpha_raw<<<efb, 256, 0, stream>>>(ei, ea, loopsum, deg, Mbuf, 0, als, ald, alpha, amax, E, N);
    k_alpha_exp<<<efb, 256, 0, stream>>>(ei, alpha, amax, denom, E, N);
    k_agg<128><<<(N + 3) / 4, 256, 0, stream>>>(h1, alpha, denom, offsets, csr_src, csr_eid, b1, out1, E, N);

    // ---------- layer 2 ----------
    k_gemm<32, 64><<<(N + 63) / 64, 256, 0, stream>>>(out1, W2, h2, N);
    k_al<32><<<(N * 4 + 255) / 256, 256, 0, stream>>>(h2, as2, ad2, als, ald, N);
    hipMemsetAsync(amax, 0xFF, (size_t)N * 16, stream);
    hipMemsetAsync(denom, 0,   (size_t)N * 16, stream);
    k_alpha_raw<<<efb, 256, 0, stream>>>(ei, ea, loopsum, deg, Mbuf, 1, als, ald, alpha, amax, E, N);
    k_alpha_exp<<<efb, 256, 0, stream>>>(ei, alpha, amax, denom, E, N);
    k_agg<32><<<(N + 3) / 4, 256, 0, stream>>>(h2, alpha, denom, offsets, csr_src, csr_eid, b2, out2, E, N);

    // ---------- pool + fc ----------
    k_pool<<<(N * 32 + 255) / 256, 256, 0, stream>>>(out2, batch, pooled, cnt, N);
    k_final<<<1, 640, 0, stream>>>(pooled, cnt, Wfc, bfc, out);
}

// Round 2
// 955.422 us; speedup vs baseline: 3.6319x; 3.6319x over previous
//
#include <hip/hip_runtime.h>
#include <math.h>

typedef float4 f4;
#define NEG_SLOPE 0.2f

// ---- M[d][h] = sum_c We[d, h*C+c] * ae[h, c]   (M1: 16x4 from We1/ae1, M2 from We2/ae2)
__global__ void k_prep(const float* __restrict__ We1, const float* __restrict__ ae1,
                       const float* __restrict__ We2, const float* __restrict__ ae2,
                       float* __restrict__ M) {
    int t = threadIdx.x;                  // 128 threads
    if (t >= 128) return;
    int sel = t >> 6, i = t & 63, d = i >> 2, h = i & 3;
    const float* W  = sel ? We2 : We1;
    const float* ae = sel ? ae2 : ae1;
    int C = sel ? 8 : 32, ncol = sel ? 32 : 128;
    float s = 0.f;
    for (int c = 0; c < C; ++c) s += W[d * ncol + h * C + c] * ae[h * C + c];
    M[sel * 64 + d * 4 + h] = s;
}

// ---- deg[dst]++ per real edge (int atomics only)
__global__ void k_deg(const int* __restrict__ ei, int* __restrict__ deg, int E) {
    int e = blockIdx.x * 256 + threadIdx.x;
    if (e < E) atomicAdd(&deg[ei[E + e]], 1);
}

// ---- exclusive scan of deg -> offsets[0..N], cursor copy. One block of 1024.
__global__ void k_scan(const int* __restrict__ deg, int* __restrict__ offsets,
                       int* __restrict__ cursor, int N) {
    __shared__ int ts[1024];
    int t = threadIdx.x;
    int CH = (N + 1023) / 1024;
    int lo = t * CH, hi = min(lo + CH, N);
    int s = 0;
    for (int i = lo; i < hi; ++i) s += deg[i];
    ts[t] = s;
    __syncthreads();
    for (int off = 1; off < 1024; off <<= 1) {
        int v = (t >= off) ? ts[t - off] : 0;
        __syncthreads();
        ts[t] += v;
        __syncthreads();
    }
    int run = (t == 0) ? 0 : ts[t - 1];
    for (int i = lo; i < hi; ++i) { offsets[i] = run; cursor[i] = run; run += deg[i]; }
    if (t == 1023) offsets[N] = ts[1023];
}

// ---- fill CSR (by dst): src node + per-edge al_e for BOTH layers, in CSR slot order
__global__ void k_fill_ale(const int* __restrict__ ei, const float* __restrict__ ea,
                           const float* __restrict__ Mbuf, int* __restrict__ cursor,
                           int* __restrict__ csr_src,
                           float* __restrict__ ale1_csr, float* __restrict__ ale2_csr,
                           int E) {
    __shared__ float Ms[128];
    if (threadIdx.x < 128) Ms[threadIdx.x] = Mbuf[threadIdx.x];
    __syncthreads();
    int e = blockIdx.x * 256 + threadIdx.x;
    if (e >= E) return;
    int sr = ei[e], d = ei[E + e];
    const f4* row = (const f4*)(ea + (size_t)e * 16);
    f4 r0 = row[0], r1 = row[1], r2 = row[2], r3 = row[3];
    float a[16] = { r0.x, r0.y, r0.z, r0.w, r1.x, r1.y, r1.z, r1.w,
                    r2.x, r2.y, r2.z, r2.w, r3.x, r3.y, r3.z, r3.w };
    float s10 = 0.f, s11 = 0.f, s12 = 0.f, s13 = 0.f;
    float s20 = 0.f, s21 = 0.f, s22 = 0.f, s23 = 0.f;
#pragma unroll
    for (int dd = 0; dd < 16; ++dd) {
        float av = a[dd];
        s10 += av * Ms[dd * 4 + 0]; s11 += av * Ms[dd * 4 + 1];
        s12 += av * Ms[dd * 4 + 2]; s13 += av * Ms[dd * 4 + 3];
        s20 += av * Ms[64 + dd * 4 + 0]; s21 += av * Ms[64 + dd * 4 + 1];
        s22 += av * Ms[64 + dd * 4 + 2]; s23 += av * Ms[64 + dd * 4 + 3];
    }
    int slot = atomicAdd(&cursor[d], 1);
    csr_src[slot] = sr;
    f4 o1; o1.x = s10; o1.y = s11; o1.z = s12; o1.w = s13;
    f4 o2; o2.x = s20; o2.y = s21; o2.z = s22; o2.w = s23;
    ((f4*)ale1_csr)[slot] = o1;
    ((f4*)ale2_csr)[slot] = o2;
}

// ---- simple LDS-tiled fp32 GEMM: Hout[N,NOUT] = X[N,128] @ W[128,NOUT]
template<int NOUT, int ROWS>
__global__ __launch_bounds__(256) void k_gemm(const float* __restrict__ X,
                                              const float* __restrict__ W,
                                              float* __restrict__ Hout, int N) {
    __shared__ __align__(16) float xs[ROWS][128];
    int row0 = blockIdx.x * ROWS;
    int tid = threadIdx.x;
    constexpr int NF4 = ROWS * 32;
    const f4* x4 = (const f4*)X;
    for (int i = tid; i < NF4; i += 256) {
        int r = i >> 5, k4 = i & 31;
        f4 v;
        if (row0 + r < N) v = x4[(size_t)(row0 + r) * 32 + k4];
        else { v.x = v.y = v.z = v.w = 0.f; }
        ((f4*)&xs[r][0])[k4] = v;
    }
    __syncthreads();
    constexpr int GRP = 256 / NOUT;
    constexpr int PR  = ROWS / GRP;
    int col = tid % NOUT, rg = tid / NOUT;
    float acc[PR];
#pragma unroll
    for (int r = 0; r < PR; ++r) acc[r] = 0.f;
    for (int k = 0; k < 128; ++k) {
        float w = W[k * NOUT + col];
#pragma unroll
        for (int r = 0; r < PR; ++r) acc[r] += xs[rg + r * GRP][k] * w;
    }
#pragma unroll
    for (int r = 0; r < PR; ++r) {
        int row = row0 + rg + r * GRP;
        if (row < N) Hout[(size_t)row * NOUT + col] = acc[r];
    }
}

// ---- per (node, head): al_src/al_dst from h
template<int C>
__global__ void k_al(const float* __restrict__ Hm, const float* __restrict__ as_,
                     const float* __restrict__ ad_, float* __restrict__ als,
                     float* __restrict__ ald, int N) {
    int idx = blockIdx.x * 256 + threadIdx.x;
    int n = idx >> 2, h = idx & 3;
    if (n >= N) return;
    constexpr int CH = C / 4;
    const float* hr = Hm + (size_t)n * C + h * CH;
    float a = 0.f, b = 0.f;
#pragma unroll
    for (int c = 0; c < CH; ++c) { float v = hr[c]; a += v * as_[h * CH + c]; b += v * ad_[h * CH + c]; }
    als[n * 4 + h] = a;
    ald[n * 4 + h] = b;
}

// ---- fused edge-softmax + aggregation + self-loop + bias + relu, wave-per-node, atomic-free
// out[n,c] = relu( (sum_e exp(v_e)*h[src_e,c] + exp(v_self)*h[n,c]) / (sum exp + 1e-16) + bias[c] )
// v_e = leaky(als[src]+ald[n]+ale_csr[e]);  v_self uses (sum ale)/deg  (linearity of al_e)
template<int C>
__global__ __launch_bounds__(256) void k_aggf(const float* __restrict__ Hm,
                                              const float* __restrict__ als,
                                              const float* __restrict__ ald,
                                              const float* __restrict__ ale_csr,
                                              const int* __restrict__ offsets,
                                              const int* __restrict__ csr_src,
                                              const float* __restrict__ bias,
                                              float* __restrict__ Out, int N) {
    int n = (blockIdx.x * 256 + threadIdx.x) >> 6;
    int lane = threadIdx.x & 63;
    if (n >= N) return;
    int s0 = offsets[n], s1 = offsets[n + 1];
    float rdeg = 1.f / fmaxf((float)(s1 - s0), 1.f);
    if constexpr (C == 128) {
        int c0 = lane, c1 = lane + 64;
        int h0 = lane >> 5, h1 = 2 + (lane >> 5);
        float aldn0 = ald[n * 4 + h0], aldn1 = ald[n * 4 + h1];
        float acc0 = 0.f, acc1 = 0.f, den0 = 0.f, den1 = 0.f, asum0 = 0.f, asum1 = 0.f;
        for (int s = s0; s < s1; ++s) {
            int src = csr_src[s];
            float ale0 = ale_csr[s * 4 + h0], ale1v = ale_csr[s * 4 + h1];
            float v0 = als[src * 4 + h0] + aldn0 + ale0;
            float v1 = als[src * 4 + h1] + aldn1 + ale1v;
            v0 = (v0 > 0.f) ? v0 : NEG_SLOPE * v0;
            v1 = (v1 > 0.f) ? v1 : NEG_SLOPE * v1;
            float e0 = __expf(v0), e1 = __expf(v1);
            const float* hr = Hm + (size_t)src * 128;
            acc0 += e0 * hr[c0]; acc1 += e1 * hr[c1];
            den0 += e0; den1 += e1;
            asum0 += ale0; asum1 += ale1v;
        }
        float v0 = als[n * 4 + h0] + aldn0 + asum0 * rdeg;
        float v1 = als[n * 4 + h1] + aldn1 + asum1 * rdeg;
        v0 = (v0 > 0.f) ? v0 : NEG_SLOPE * v0;
        v1 = (v1 > 0.f) ? v1 : NEG_SLOPE * v1;
        float e0 = __expf(v0), e1 = __expf(v1);
        const float* hn = Hm + (size_t)n * 128;
        acc0 += e0 * hn[c0]; acc1 += e1 * hn[c1];
        den0 += e0; den1 += e1;
        Out[(size_t)n * 128 + c0] = fmaxf(acc0 / (den0 + 1e-16f) + bias[c0], 0.f);
        Out[(size_t)n * 128 + c1] = fmaxf(acc1 / (den1 + 1e-16f) + bias[c1], 0.f);
    } else {
        int c = lane & 31, half = lane >> 5, h = c >> 3;
        float aldn = ald[n * 4 + h];
        float acc = 0.f, den = 0.f, asum = 0.f;
        for (int s = s0 + half; s < s1; s += 2) {
            int src = csr_src[s];
            float alev = ale_csr[s * 4 + h];
            float v = als[src * 4 + h] + aldn + alev;
            v = (v > 0.f) ? v : NEG_SLOPE * v;
            float ee = __expf(v);
            acc += ee * Hm[(size_t)src * 32 + c];
            den += ee; asum += alev;
        }
        acc += __shfl_xor(acc, 32);
        den += __shfl_xor(den, 32);
        asum += __shfl_xor(asum, 32);
        float v = als[n * 4 + h] + aldn + asum * rdeg;
        v = (v > 0.f) ? v : NEG_SLOPE * v;
        float ee = __expf(v);
        acc += ee * Hm[(size_t)n * 32 + c];
        den += ee;
        if (half == 0) Out[(size_t)n * 32 + c] = fmaxf(acc / (den + 1e-16f) + bias[c], 0.f);
    }
}

// ---- mean pool accumulation
__global__ void k_pool(const float* __restrict__ out2, const int* __restrict__ batch,
                       float* __restrict__ pooled, int* __restrict__ cnt, int N) {
    int idx = blockIdx.x * 256 + threadIdx.x;
    int n = idx >> 5, c = idx & 31;
    if (n >= N) return;
    int g = batch[n];
    unsafeAtomicAdd(&pooled[g * 32 + c], out2[(size_t)n * 32 + c]);
    if (c == 0) atomicAdd(&cnt[g], 1);
}

// ---- final: out[g,cls] = (pooled[g]/cnt[g]) @ Wfc + bfc
__global__ void k_final(const float* __restrict__ pooled, const int* __restrict__ cnt,
                        const float* __restrict__ Wfc, const float* __restrict__ bfc,
                        float* __restrict__ out) {
    int t = threadIdx.x;
    if (t >= 640) return;
    int g = t / 10, cls = t % 10;
    float rc = 1.f / fmaxf((float)cnt[g], 1.f);
    float acc = bfc[cls];
    for (int c = 0; c < 32; ++c) acc += pooled[g * 32 + c] * rc * Wfc[c * 10 + cls];
    out[g * 10 + cls] = acc;
}

extern "C" void kernel_launch(void* const* d_in, const int* in_sizes, int n_in,
                              void* d_out, int out_size, void* d_ws, size_t ws_size,
                              hipStream_t stream) {
    const float* x    = (const float*)d_in[0];
    const int*   ei   = (const int*)  d_in[1];
    const float* ea   = (const float*)d_in[2];
    const int*   batch= (const int*)  d_in[3];
    const float* W1   = (const float*)d_in[4];
    const float* as1  = (const float*)d_in[5];
    const float* ad1  = (const float*)d_in[6];
    const float* We1  = (const float*)d_in[7];
    const float* ae1  = (const float*)d_in[8];
    const float* b1   = (const float*)d_in[9];
    const float* W2   = (const float*)d_in[10];
    const float* as2  = (const float*)d_in[11];
    const float* ad2  = (const float*)d_in[12];
    const float* We2  = (const float*)d_in[13];
    const float* ae2  = (const float*)d_in[14];
    const float* b2   = (const float*)d_in[15];
    const float* Wfc  = (const float*)d_in[16];
    const float* bfc  = (const float*)d_in[17];
    float* out = (float*)d_out;

    const int N  = in_sizes[3];       // 50000
    const int E  = in_sizes[1] / 2;   // 1600000

    // workspace layout (~115 MB)
    char* w = (char*)d_ws;
    size_t off = 0;
    auto alloc = [&](size_t bytes) -> void* {
        void* p = w + off;
        off = (off + bytes + 255) & ~(size_t)255;
        return p;
    };
    int*   deg      = (int*)  alloc((size_t)N * 4);
    int*   offsets  = (int*)  alloc((size_t)(N + 1) * 4);
    int*   cursor   = (int*)  alloc((size_t)N * 4);
    int*   csr_src  = (int*)  alloc((size_t)E * 4);
    float* ale1_csr = (float*)alloc((size_t)E * 4 * 4);
    float* ale2_csr = (float*)alloc((size_t)E * 4 * 4);
    float* Mbuf     = (float*)alloc(128 * 4);
    float* h1       = (float*)alloc((size_t)N * 128 * 4);
    float* out1     = (float*)alloc((size_t)N * 128 * 4);
    float* als      = (float*)alloc((size_t)N * 4 * 4);
    float* ald      = (float*)alloc((size_t)N * 4 * 4);
    int*   cnt      = (int*)  alloc(64 * 4);
    float* pooled   = (float*)alloc(64 * 32 * 4);
    float* h2   = h1;   // h1 dead after layer-1 aggregation
    float* out2 = out1; // out1 dead after layer-2 GEMM

    const int eb = (E + 255) / 256;

    hipMemsetAsync(deg,    0, (size_t)N * 4, stream);
    hipMemsetAsync(cnt,    0, 64 * 4, stream);
    hipMemsetAsync(pooled, 0, 64 * 32 * 4, stream);

    k_prep<<<1, 128, 0, stream>>>(We1, ae1, We2, ae2, Mbuf);
    k_deg<<<eb, 256, 0, stream>>>(ei, deg, E);
    k_scan<<<1, 1024, 0, stream>>>(deg, offsets, cursor, N);
    k_fill_ale<<<eb, 256, 0, stream>>>(ei, ea, Mbuf, cursor, csr_src, ale1_csr, ale2_csr, E);

    // ---------- layer 1 ----------
    k_gemm<128, 16><<<(N + 15) / 16, 256, 0, stream>>>(x, W1, h1, N);
    k_al<128><<<(N * 4 + 255) / 256, 256, 0, stream>>>(h1, as1, ad1, als, ald, N);
    k_aggf<128><<<(N + 3) / 4, 256, 0, stream>>>(h1, als, ald, ale1_csr, offsets, csr_src, b1, out1, N);

    // ---------- layer 2 ----------
    k_gemm<32, 64><<<(N + 63) / 64, 256, 0, stream>>>(out1, W2, h2, N);
    k_al<32><<<(N * 4 + 255) / 256, 256, 0, stream>>>(h2, as2, ad2, als, ald, N);
    k_aggf<32><<<(N + 3) / 4, 256, 0, stream>>>(h2, als, ald, ale2_csr, offsets, csr_src, b2, out2, N);

    // ---------- pool + fc ----------
    k_pool<<<(N * 32 + 255) / 256, 256, 0, stream>>>(out2, batch, pooled, cnt, N);
    k_final<<<1, 640, 0, stream>>>(pooled, cnt, Wfc, bfc, out);
}

// Round 3
// 674.270 us; speedup vs baseline: 5.1462x; 1.4170x over previous
//
#include <hip/hip_runtime.h>
#include <math.h>

typedef float4 f4;
#define NEG_SLOPE 0.2f

// ---- M[d][h] = sum_c We[d, h*C+c] * ae[h, c]   (M1: 16x4 from We1/ae1, M2 from We2/ae2)
__global__ void k_prep(const float* __restrict__ We1, const float* __restrict__ ae1,
                       const float* __restrict__ We2, const float* __restrict__ ae2,
                       float* __restrict__ M) {
    int t = threadIdx.x;                  // 128 threads
    if (t >= 128) return;
    int sel = t >> 6, i = t & 63, d = i >> 2, h = i & 3;
    const float* W  = sel ? We2 : We1;
    const float* ae = sel ? ae2 : ae1;
    int C = sel ? 8 : 32, ncol = sel ? 32 : 128;
    float s = 0.f;
    for (int c = 0; c < C; ++c) s += W[d * ncol + h * C + c] * ae[h * C + c];
    M[sel * 64 + d * 4 + h] = s;
}

// ---- deg[dst]++ per real edge (int atomics only)
__global__ void k_deg(const int* __restrict__ ei, int* __restrict__ deg, int E) {
    int e = blockIdx.x * 256 + threadIdx.x;
    if (e < E) atomicAdd(&deg[ei[E + e]], 1);
}

// ---- exclusive scan of deg -> offsets[0..N], cursor copy. One block of 1024.
__global__ void k_scan(const int* __restrict__ deg, int* __restrict__ offsets,
                       int* __restrict__ cursor, int N) {
    __shared__ int ts[1024];
    int t = threadIdx.x;
    int CH = (N + 1023) / 1024;
    int lo = t * CH, hi = min(lo + CH, N);
    int s = 0;
    for (int i = lo; i < hi; ++i) s += deg[i];
    ts[t] = s;
    __syncthreads();
    for (int off = 1; off < 1024; off <<= 1) {
        int v = (t >= off) ? ts[t - off] : 0;
        __syncthreads();
        ts[t] += v;
        __syncthreads();
    }
    int run = (t == 0) ? 0 : ts[t - 1];
    for (int i = lo; i < hi; ++i) { offsets[i] = run; cursor[i] = run; run += deg[i]; }
    if (t == 1023) offsets[N] = ts[1023];
}

// ---- fill CSR (by dst): src node + per-edge al_e for BOTH layers, in CSR slot order
__global__ void k_fill_ale(const int* __restrict__ ei, const float* __restrict__ ea,
                           const float* __restrict__ Mbuf, int* __restrict__ cursor,
                           int* __restrict__ csr_src,
                           float* __restrict__ ale1_csr, float* __restrict__ ale2_csr,
                           int E) {
    __shared__ float Ms[128];
    if (threadIdx.x < 128) Ms[threadIdx.x] = Mbuf[threadIdx.x];
    __syncthreads();
    int e = blockIdx.x * 256 + threadIdx.x;
    if (e >= E) return;
    int sr = ei[e], d = ei[E + e];
    const f4* row = (const f4*)(ea + (size_t)e * 16);
    f4 r0 = row[0], r1 = row[1], r2 = row[2], r3 = row[3];
    float a[16] = { r0.x, r0.y, r0.z, r0.w, r1.x, r1.y, r1.z, r1.w,
                    r2.x, r2.y, r2.z, r2.w, r3.x, r3.y, r3.z, r3.w };
    float s10 = 0.f, s11 = 0.f, s12 = 0.f, s13 = 0.f;
    float s20 = 0.f, s21 = 0.f, s22 = 0.f, s23 = 0.f;
#pragma unroll
    for (int dd = 0; dd < 16; ++dd) {
        float av = a[dd];
        s10 += av * Ms[dd * 4 + 0]; s11 += av * Ms[dd * 4 + 1];
        s12 += av * Ms[dd * 4 + 2]; s13 += av * Ms[dd * 4 + 3];
        s20 += av * Ms[64 + dd * 4 + 0]; s21 += av * Ms[64 + dd * 4 + 1];
        s22 += av * Ms[64 + dd * 4 + 2]; s23 += av * Ms[64 + dd * 4 + 3];
    }
    int slot = atomicAdd(&cursor[d], 1);
    csr_src[slot] = sr;
    f4 o1; o1.x = s10; o1.y = s11; o1.z = s12; o1.w = s13;
    f4 o2; o2.x = s20; o2.y = s21; o2.z = s22; o2.w = s23;
    ((f4*)ale1_csr)[slot] = o1;
    ((f4*)ale2_csr)[slot] = o2;
}

// ---- simple LDS-tiled fp32 GEMM: Hout[N,NOUT] = X[N,128] @ W[128,NOUT]
template<int NOUT, int ROWS>
__global__ __launch_bounds__(256) void k_gemm(const float* __restrict__ X,
                                              const float* __restrict__ W,
                                              float* __restrict__ Hout, int N) {
    __shared__ __align__(16) float xs[ROWS][128];
    int row0 = blockIdx.x * ROWS;
    int tid = threadIdx.x;
    constexpr int NF4 = ROWS * 32;
    const f4* x4 = (const f4*)X;
    for (int i = tid; i < NF4; i += 256) {
        int r = i >> 5, k4 = i & 31;
        f4 v;
        if (row0 + r < N) v = x4[(size_t)(row0 + r) * 32 + k4];
        else { v.x = v.y = v.z = v.w = 0.f; }
        ((f4*)&xs[r][0])[k4] = v;
    }
    __syncthreads();
    constexpr int GRP = 256 / NOUT;
    constexpr int PR  = ROWS / GRP;
    int col = tid % NOUT, rg = tid / NOUT;
    float acc[PR];
#pragma unroll
    for (int r = 0; r < PR; ++r) acc[r] = 0.f;
    for (int k = 0; k < 128; ++k) {
        float w = W[k * NOUT + col];
#pragma unroll
        for (int r = 0; r < PR; ++r) acc[r] += xs[rg + r * GRP][k] * w;
    }
#pragma unroll
    for (int r = 0; r < PR; ++r) {
        int row = row0 + rg + r * GRP;
        if (row < N) Hout[(size_t)row * NOUT + col] = acc[r];
    }
}

// ---- per (node, head): al_src/al_dst from h
template<int C>
__global__ void k_al(const float* __restrict__ Hm, const float* __restrict__ as_,
                     const float* __restrict__ ad_, float* __restrict__ als,
                     float* __restrict__ ald, int N) {
    int idx = blockIdx.x * 256 + threadIdx.x;
    int n = idx >> 2, h = idx & 3;
    if (n >= N) return;
    constexpr int CH = C / 4;
    const float* hr = Hm + (size_t)n * C + h * CH;
    float a = 0.f, b = 0.f;
#pragma unroll
    for (int c = 0; c < CH; ++c) { float v = hr[c]; a += v * as_[h * CH + c]; b += v * ad_[h * CH + c]; }
    als[n * 4 + h] = a;
    ald[n * 4 + h] = b;
}

// ---- fused edge-softmax + aggregation + self-loop + bias + relu, wave-per-node, atomic-free
template<int C>
__global__ __launch_bounds__(256) void k_aggf(const float* __restrict__ Hm,
                                              const float* __restrict__ als,
                                              const float* __restrict__ ald,
                                              const float* __restrict__ ale_csr,
                                              const int* __restrict__ offsets,
                                              const int* __restrict__ csr_src,
                                              const float* __restrict__ bias,
                                              float* __restrict__ Out, int N) {
    int n = (blockIdx.x * 256 + threadIdx.x) >> 6;
    int lane = threadIdx.x & 63;
    if (n >= N) return;
    int s0 = offsets[n], s1 = offsets[n + 1];
    float rdeg = 1.f / fmaxf((float)(s1 - s0), 1.f);
    if constexpr (C == 128) {
        int c0 = lane, c1 = lane + 64;
        int h0 = lane >> 5, h1 = 2 + (lane >> 5);
        float aldn0 = ald[n * 4 + h0], aldn1 = ald[n * 4 + h1];
        float acc0 = 0.f, acc1 = 0.f, den0 = 0.f, den1 = 0.f, asum0 = 0.f, asum1 = 0.f;
        for (int s = s0; s < s1; ++s) {
            int src = csr_src[s];
            float ale0 = ale_csr[s * 4 + h0], ale1v = ale_csr[s * 4 + h1];
            float v0 = als[src * 4 + h0] + aldn0 + ale0;
            float v1 = als[src * 4 + h1] + aldn1 + ale1v;
            v0 = (v0 > 0.f) ? v0 : NEG_SLOPE * v0;
            v1 = (v1 > 0.f) ? v1 : NEG_SLOPE * v1;
            float e0 = __expf(v0), e1 = __expf(v1);
            const float* hr = Hm + (size_t)src * 128;
            acc0 += e0 * hr[c0]; acc1 += e1 * hr[c1];
            den0 += e0; den1 += e1;
            asum0 += ale0; asum1 += ale1v;
        }
        float v0 = als[n * 4 + h0] + aldn0 + asum0 * rdeg;
        float v1 = als[n * 4 + h1] + aldn1 + asum1 * rdeg;
        v0 = (v0 > 0.f) ? v0 : NEG_SLOPE * v0;
        v1 = (v1 > 0.f) ? v1 : NEG_SLOPE * v1;
        float e0 = __expf(v0), e1 = __expf(v1);
        const float* hn = Hm + (size_t)n * 128;
        acc0 += e0 * hn[c0]; acc1 += e1 * hn[c1];
        den0 += e0; den1 += e1;
        Out[(size_t)n * 128 + c0] = fmaxf(acc0 / (den0 + 1e-16f) + bias[c0], 0.f);
        Out[(size_t)n * 128 + c1] = fmaxf(acc1 / (den1 + 1e-16f) + bias[c1], 0.f);
    } else {
        int c = lane & 31, half = lane >> 5, h = c >> 3;
        float aldn = ald[n * 4 + h];
        float acc = 0.f, den = 0.f, asum = 0.f;
        for (int s = s0 + half; s < s1; s += 2) {
            int src = csr_src[s];
            float alev = ale_csr[s * 4 + h];
            float v = als[src * 4 + h] + aldn + alev;
            v = (v > 0.f) ? v : NEG_SLOPE * v;
            float ee = __expf(v);
            acc += ee * Hm[(size_t)src * 32 + c];
            den += ee; asum += alev;
        }
        acc += __shfl_xor(acc, 32);
        den += __shfl_xor(den, 32);
        asum += __shfl_xor(asum, 32);
        float v = als[n * 4 + h] + aldn + asum * rdeg;
        v = (v > 0.f) ? v : NEG_SLOPE * v;
        float ee = __expf(v);
        acc += ee * Hm[(size_t)n * 32 + c];
        den += ee;
        if (half == 0) Out[(size_t)n * 32 + c] = fmaxf(acc / (den + 1e-16f) + bias[c], 0.f);
    }
}

// ---- group boundaries: gstart[g] = lower_bound(batch, g), g in [0,64]
__global__ void k_gbound(const int* __restrict__ batch, int* __restrict__ gstart, int N, int G) {
    int g = threadIdx.x;
    if (g > G) return;
    int lo = 0, hi = N;
    while (lo < hi) {
        int mid = (lo + hi) >> 1;
        if (batch[mid] < g) lo = mid + 1; else hi = mid;
    }
    gstart[g] = lo;
}

// ---- atomic-free mean pool: one block per group, contiguous slab reduce
__global__ __launch_bounds__(256) void k_pool_grp(const float* __restrict__ out2,
                                                  const int* __restrict__ gstart,
                                                  float* __restrict__ pooled, int G) {
    __shared__ float red[8][32];
    int g = blockIdx.x;
    int t = threadIdx.x, c = t & 31, r = t >> 5;   // r in 0..7
    int s0 = gstart[g], s1 = gstart[g + 1];
    float acc = 0.f;
    for (int n = s0 + r; n < s1; n += 8) acc += out2[(size_t)n * 32 + c];
    red[r][c] = acc;
    __syncthreads();
    if (r == 0) {
        float s = red[0][c];
#pragma unroll
        for (int i = 1; i < 8; ++i) s += red[i][c];
        pooled[g * 32 + c] = s;
    }
}

// ---- final: out[g,cls] = (pooled[g]/cnt[g]) @ Wfc + bfc   (cnt from gstart diffs)
__global__ void k_final(const float* __restrict__ pooled, const int* __restrict__ gstart,
                        const float* __restrict__ Wfc, const float* __restrict__ bfc,
                        float* __restrict__ out) {
    int t = threadIdx.x;
    if (t >= 640) return;
    int g = t / 10, cls = t % 10;
    float rc = 1.f / fmaxf((float)(gstart[g + 1] - gstart[g]), 1.f);
    float acc = bfc[cls];
    for (int c = 0; c < 32; ++c) acc += pooled[g * 32 + c] * rc * Wfc[c * 10 + cls];
    out[g * 10 + cls] = acc;
}

extern "C" void kernel_launch(void* const* d_in, const int* in_sizes, int n_in,
                              void* d_out, int out_size, void* d_ws, size_t ws_size,
                              hipStream_t stream) {
    const float* x    = (const float*)d_in[0];
    const int*   ei   = (const int*)  d_in[1];
    const float* ea   = (const float*)d_in[2];
    const int*   batch= (const int*)  d_in[3];
    const float* W1   = (const float*)d_in[4];
    const float* as1  = (const float*)d_in[5];
    const float* ad1  = (const float*)d_in[6];
    const float* We1  = (const float*)d_in[7];
    const float* ae1  = (const float*)d_in[8];
    const float* b1   = (const float*)d_in[9];
    const float* W2   = (const float*)d_in[10];
    const float* as2  = (const float*)d_in[11];
    const float* ad2  = (const float*)d_in[12];
    const float* We2  = (const float*)d_in[13];
    const float* ae2  = (const float*)d_in[14];
    const float* b2   = (const float*)d_in[15];
    const float* Wfc  = (const float*)d_in[16];
    const float* bfc  = (const float*)d_in[17];
    float* out = (float*)d_out;

    const int N  = in_sizes[3];       // 50000
    const int E  = in_sizes[1] / 2;   // 1600000
    const int G  = 64;

    char* w = (char*)d_ws;
    size_t off = 0;
    auto alloc = [&](size_t bytes) -> void* {
        void* p = w + off;
        off = (off + bytes + 255) & ~(size_t)255;
        return p;
    };
    int*   deg      = (int*)  alloc((size_t)N * 4);
    int*   offsets  = (int*)  alloc((size_t)(N + 1) * 4);
    int*   cursor   = (int*)  alloc((size_t)N * 4);
    int*   csr_src  = (int*)  alloc((size_t)E * 4);
    float* ale1_csr = (float*)alloc((size_t)E * 4 * 4);
    float* ale2_csr = (float*)alloc((size_t)E * 4 * 4);
    float* Mbuf     = (float*)alloc(128 * 4);
    float* h1       = (float*)alloc((size_t)N * 128 * 4);
    float* out1     = (float*)alloc((size_t)N * 128 * 4);
    float* als      = (float*)alloc((size_t)N * 4 * 4);
    float* ald      = (float*)alloc((size_t)N * 4 * 4);
    int*   gstart   = (int*)  alloc((G + 1) * 4);
    float* pooled   = (float*)alloc(G * 32 * 4);
    float* h2   = h1;   // h1 dead after layer-1 aggregation
    float* out2 = out1; // out1 dead after layer-2 GEMM

    const int eb = (E + 255) / 256;

    hipMemsetAsync(deg, 0, (size_t)N * 4, stream);

    k_prep<<<1, 128, 0, stream>>>(We1, ae1, We2, ae2, Mbuf);
    k_deg<<<eb, 256, 0, stream>>>(ei, deg, E);
    k_scan<<<1, 1024, 0, stream>>>(deg, offsets, cursor, N);
    k_fill_ale<<<eb, 256, 0, stream>>>(ei, ea, Mbuf, cursor, csr_src, ale1_csr, ale2_csr, E);
    k_gbound<<<1, 128, 0, stream>>>(batch, gstart, N, G);

    // ---------- layer 1 ----------
    k_gemm<128, 16><<<(N + 15) / 16, 256, 0, stream>>>(x, W1, h1, N);
    k_al<128><<<(N * 4 + 255) / 256, 256, 0, stream>>>(h1, as1, ad1, als, ald, N);
    k_aggf<128><<<(N + 3) / 4, 256, 0, stream>>>(h1, als, ald, ale1_csr, offsets, csr_src, b1, out1, N);

    // ---------- layer 2 ----------
    k_gemm<32, 64><<<(N + 63) / 64, 256, 0, stream>>>(out1, W2, h2, N);
    k_al<32><<<(N * 4 + 255) / 256, 256, 0, stream>>>(h2, as2, ad2, als, ald, N);
    k_aggf<32><<<(N + 3) / 4, 256, 0, stream>>>(h2, als, ald, ale2_csr, offsets, csr_src, b2, out2, N);

    // ---------- pool + fc ----------
    k_pool_grp<<<G, 256, 0, stream>>>(out2, gstart, pooled, G);
    k_final<<<1, 640, 0, stream>>>(pooled, gstart, Wfc, bfc, out);
}

// Round 4
// 620.611 us; speedup vs baseline: 5.5912x; 1.0865x over previous
//
#include <hip/hip_runtime.h>
#include <hip/hip_fp16.h>
#include <math.h>

typedef float4 f4;
#define NEG_SLOPE 0.2f

// ---- M[d][h] = sum_c We[d, h*C+c] * ae[h, c]   (M1: 16x4 from We1/ae1, M2 from We2/ae2)
__global__ void k_prep(const float* __restrict__ We1, const float* __restrict__ ae1,
                       const float* __restrict__ We2, const float* __restrict__ ae2,
                       float* __restrict__ M) {
    int t = threadIdx.x;                  // 128 threads
    if (t >= 128) return;
    int sel = t >> 6, i = t & 63, d = i >> 2, h = i & 3;
    const float* W  = sel ? We2 : We1;
    const float* ae = sel ? ae2 : ae1;
    int C = sel ? 8 : 32, ncol = sel ? 32 : 128;
    float s = 0.f;
    for (int c = 0; c < C; ++c) s += W[d * ncol + h * C + c] * ae[h * C + c];
    M[sel * 64 + d * 4 + h] = s;
}

// ---- deg[dst]++ per real edge (int atomics only)
__global__ void k_deg(const int* __restrict__ ei, int* __restrict__ deg, int E) {
    int e = blockIdx.x * 256 + threadIdx.x;
    if (e < E) atomicAdd(&deg[ei[E + e]], 1);
}

// ---- exclusive scan of deg -> offsets[0..N], cursor copy. One block of 1024.
__global__ void k_scan(const int* __restrict__ deg, int* __restrict__ offsets,
                       int* __restrict__ cursor, int N) {
    __shared__ int ts[1024];
    int t = threadIdx.x;
    int CH = (N + 1023) / 1024;
    int lo = t * CH, hi = min(lo + CH, N);
    int s = 0;
    for (int i = lo; i < hi; ++i) s += deg[i];
    ts[t] = s;
    __syncthreads();
    for (int off = 1; off < 1024; off <<= 1) {
        int v = (t >= off) ? ts[t - off] : 0;
        __syncthreads();
        ts[t] += v;
        __syncthreads();
    }
    int run = (t == 0) ? 0 : ts[t - 1];
    for (int i = lo; i < hi; ++i) { offsets[i] = run; cursor[i] = run; run += deg[i]; }
    if (t == 1023) offsets[N] = ts[1023];
}

// ---- fill CSR (by dst): src node + per-edge al_e for BOTH layers, in CSR slot order
__global__ void k_fill_ale(const int* __restrict__ ei, const float* __restrict__ ea,
                           const float* __restrict__ Mbuf, int* __restrict__ cursor,
                           int* __restrict__ csr_src,
                           float* __restrict__ ale1_csr, float* __restrict__ ale2_csr,
                           int E) {
    __shared__ float Ms[128];
    if (threadIdx.x < 128) Ms[threadIdx.x] = Mbuf[threadIdx.x];
    __syncthreads();
    int e = blockIdx.x * 256 + threadIdx.x;
    if (e >= E) return;
    int sr = ei[e], d = ei[E + e];
    const f4* row = (const f4*)(ea + (size_t)e * 16);
    f4 r0 = row[0], r1 = row[1], r2 = row[2], r3 = row[3];
    float a[16] = { r0.x, r0.y, r0.z, r0.w, r1.x, r1.y, r1.z, r1.w,
                    r2.x, r2.y, r2.z, r2.w, r3.x, r3.y, r3.z, r3.w };
    float s10 = 0.f, s11 = 0.f, s12 = 0.f, s13 = 0.f;
    float s20 = 0.f, s21 = 0.f, s22 = 0.f, s23 = 0.f;
#pragma unroll
    for (int dd = 0; dd < 16; ++dd) {
        float av = a[dd];
        s10 += av * Ms[dd * 4 + 0]; s11 += av * Ms[dd * 4 + 1];
        s12 += av * Ms[dd * 4 + 2]; s13 += av * Ms[dd * 4 + 3];
        s20 += av * Ms[64 + dd * 4 + 0]; s21 += av * Ms[64 + dd * 4 + 1];
        s22 += av * Ms[64 + dd * 4 + 2]; s23 += av * Ms[64 + dd * 4 + 3];
    }
    int slot = atomicAdd(&cursor[d], 1);
    csr_src[slot] = sr;
    f4 o1; o1.x = s10; o1.y = s11; o1.z = s12; o1.w = s13;
    f4 o2; o2.x = s20; o2.y = s21; o2.z = s22; o2.w = s23;
    ((f4*)ale1_csr)[slot] = o1;
    ((f4*)ale2_csr)[slot] = o2;
}

// ---- LDS-tiled fp32 GEMM, fp16 output: Hout[N,NOUT] = half(X[N,128] @ W[128,NOUT])
template<int NOUT, int ROWS>
__global__ __launch_bounds__(256) void k_gemm(const float* __restrict__ X,
                                              const float* __restrict__ W,
                                              __half* __restrict__ Hout, int N) {
    __shared__ __align__(16) float xs[ROWS][128];
    int row0 = blockIdx.x * ROWS;
    int tid = threadIdx.x;
    constexpr int NF4 = ROWS * 32;
    const f4* x4 = (const f4*)X;
    for (int i = tid; i < NF4; i += 256) {
        int r = i >> 5, k4 = i & 31;
        f4 v;
        if (row0 + r < N) v = x4[(size_t)(row0 + r) * 32 + k4];
        else { v.x = v.y = v.z = v.w = 0.f; }
        ((f4*)&xs[r][0])[k4] = v;
    }
    __syncthreads();
    constexpr int GRP = 256 / NOUT;
    constexpr int PR  = ROWS / GRP;
    int col = tid % NOUT, rg = tid / NOUT;
    float acc[PR];
#pragma unroll
    for (int r = 0; r < PR; ++r) acc[r] = 0.f;
    for (int k = 0; k < 128; ++k) {
        float w = W[k * NOUT + col];
#pragma unroll
        for (int r = 0; r < PR; ++r) acc[r] += xs[rg + r * GRP][k] * w;
    }
#pragma unroll
    for (int r = 0; r < PR; ++r) {
        int row = row0 + rg + r * GRP;
        if (row < N) Hout[(size_t)row * NOUT + col] = __float2half(acc[r]);
    }
}

// ---- per (node, head): al_src/al_dst from fp16 h
template<int C>
__global__ void k_al(const __half* __restrict__ Hm, const float* __restrict__ as_,
                     const float* __restrict__ ad_, float* __restrict__ als,
                     float* __restrict__ ald, int N) {
    int idx = blockIdx.x * 256 + threadIdx.x;
    int n = idx >> 2, h = idx & 3;
    if (n >= N) return;
    constexpr int CH = C / 4;
    const __half2* h2p = (const __half2*)(Hm + (size_t)n * C + h * CH);
    float a = 0.f, b = 0.f;
#pragma unroll
    for (int c = 0; c < CH / 2; ++c) {
        float2 v = __half22float2(h2p[c]);
        a += v.x * as_[h * CH + 2 * c] + v.y * as_[h * CH + 2 * c + 1];
        b += v.x * ad_[h * CH + 2 * c] + v.y * ad_[h * CH + 2 * c + 1];
    }
    als[n * 4 + h] = a;
    ald[n * 4 + h] = b;
}

// ---- wave-per-node: transform ale_csr (in place) -> exp(leaky(als[src]+ald[n]+ale)),
//      emit rden[n][h] = 1/(sum_exp + e_self + 1e-16), selfa[n][h] = e_self
__global__ __launch_bounds__(256) void k_alpha_node(float* __restrict__ ale_csr,
                                                    const int* __restrict__ csr_src,
                                                    const float* __restrict__ als,
                                                    const float* __restrict__ ald,
                                                    const int* __restrict__ offsets,
                                                    float* __restrict__ rden,
                                                    float* __restrict__ selfa, int N) {
    int n = (blockIdx.x * 256 + threadIdx.x) >> 6;
    int lane = threadIdx.x & 63;
    if (n >= N) return;
    int j = lane >> 2, h = lane & 3;   // 16 edges x 4 heads per iteration
    int s0 = offsets[n], s1 = offsets[n + 1];
    float aldn = ald[n * 4 + h];
    float den = 0.f, asum = 0.f;
    for (int base = s0; base < s1; base += 16) {
        int s = base + j;
        if (s < s1) {
            int src = csr_src[s];
            float ale = ale_csr[s * 4 + h];
            float v = als[src * 4 + h] + aldn + ale;
            v = (v > 0.f) ? v : NEG_SLOPE * v;
            float e = __expf(v);
            ale_csr[s * 4 + h] = e;
            den += e; asum += ale;
        }
    }
    den  += __shfl_xor(den, 4);  den  += __shfl_xor(den, 8);
    den  += __shfl_xor(den, 16); den  += __shfl_xor(den, 32);
    asum += __shfl_xor(asum, 4);  asum += __shfl_xor(asum, 8);
    asum += __shfl_xor(asum, 16); asum += __shfl_xor(asum, 32);
    if (j == 0) {
        float rdeg = 1.f / fmaxf((float)(s1 - s0), 1.f);
        float v = als[n * 4 + h] + aldn + asum * rdeg;
        v = (v > 0.f) ? v : NEG_SLOPE * v;
        float es = __expf(v);
        selfa[n * 4 + h] = es;
        rden[n * 4 + h] = 1.f / (den + es + 1e-16f);
    }
}

// ---- layer-1 aggregation: pure gather-FMA, wave-per-node, fp16 h, lane -> channels {2l,2l+1}
__global__ __launch_bounds__(256) void k_aggf128(const __half* __restrict__ h16,
                                                 const float* __restrict__ alpha_csr,
                                                 const float* __restrict__ rden,
                                                 const float* __restrict__ selfa,
                                                 const int* __restrict__ offsets,
                                                 const int* __restrict__ csr_src,
                                                 const float* __restrict__ bias,
                                                 float* __restrict__ Out, int N) {
    int n = (blockIdx.x * 256 + threadIdx.x) >> 6;
    int lane = threadIdx.x & 63;
    if (n >= N) return;
    int hd = lane >> 4;                 // head of channels 2l, 2l+1
    int s0 = offsets[n], s1 = offsets[n + 1];
    const __half2* H2 = (const __half2*)h16;
    float acc0 = 0.f, acc1 = 0.f;
    for (int s = s0; s < s1; ++s) {
        int src = csr_src[s];
        float a = alpha_csr[s * 4 + hd];
        float2 hv = __half22float2(H2[(size_t)src * 64 + lane]);
        acc0 = fmaf(a, hv.x, acc0);
        acc1 = fmaf(a, hv.y, acc1);
    }
    float sa = selfa[n * 4 + hd];
    float2 hn = __half22float2(H2[(size_t)n * 64 + lane]);
    acc0 = fmaf(sa, hn.x, acc0);
    acc1 = fmaf(sa, hn.y, acc1);
    float rd = rden[n * 4 + hd];
    float2 bv = ((const float2*)bias)[lane];
    float2 o;
    o.x = fmaxf(fmaf(acc0, rd, bv.x), 0.f);
    o.y = fmaxf(fmaf(acc1, rd, bv.y), 0.f);
    ((float2*)Out)[(size_t)n * 64 + lane] = o;
}

// ---- layer-2 aggregation: 4 edges/iter across the wave, fp16 h2 (32 ch = 16 half2)
__global__ __launch_bounds__(256) void k_aggf32(const __half* __restrict__ h16,
                                                const float* __restrict__ alpha_csr,
                                                const float* __restrict__ rden,
                                                const float* __restrict__ selfa,
                                                const int* __restrict__ offsets,
                                                const int* __restrict__ csr_src,
                                                const float* __restrict__ bias,
                                                float* __restrict__ Out, int N) {
    int n = (blockIdx.x * 256 + threadIdx.x) >> 6;
    int lane = threadIdx.x & 63;
    if (n >= N) return;
    int j = lane >> 4;                  // edge sub-slot 0..3
    int p = lane & 15;                  // half2 index -> channels 2p,2p+1
    int hd = p >> 2;                    // head
    int s0 = offsets[n], s1 = offsets[n + 1];
    const __half2* H2 = (const __half2*)h16;
    float acc0 = 0.f, acc1 = 0.f;
    for (int s = s0 + j; s < s1; s += 4) {
        int src = csr_src[s];
        float a = alpha_csr[s * 4 + hd];
        float2 hv = __half22float2(H2[(size_t)src * 16 + p]);
        acc0 = fmaf(a, hv.x, acc0);
        acc1 = fmaf(a, hv.y, acc1);
    }
    acc0 += __shfl_xor(acc0, 16); acc0 += __shfl_xor(acc0, 32);
    acc1 += __shfl_xor(acc1, 16); acc1 += __shfl_xor(acc1, 32);
    if (j == 0) {
        float sa = selfa[n * 4 + hd];
        float2 hn = __half22float2(H2[(size_t)n * 16 + p]);
        acc0 = fmaf(sa, hn.x, acc0);
        acc1 = fmaf(sa, hn.y, acc1);
        float rd = rden[n * 4 + hd];
        float2 bv = ((const float2*)bias)[p];
        float2 o;
        o.x = fmaxf(fmaf(acc0, rd, bv.x), 0.f);
        o.y = fmaxf(fmaf(acc1, rd, bv.y), 0.f);
        ((float2*)Out)[(size_t)n * 16 + p] = o;
    }
}

// ---- group boundaries: gstart[g] = lower_bound(batch, g), g in [0,64]
__global__ void k_gbound(const int* __restrict__ batch, int* __restrict__ gstart, int N, int G) {
    int g = threadIdx.x;
    if (g > G) return;
    int lo = 0, hi = N;
    while (lo < hi) {
        int mid = (lo + hi) >> 1;
        if (batch[mid] < g) lo = mid + 1; else hi = mid;
    }
    gstart[g] = lo;
}

// ---- atomic-free mean pool: one block per group, contiguous slab reduce
__global__ __launch_bounds__(256) void k_pool_grp(const float* __restrict__ out2,
                                                  const int* __restrict__ gstart,
                                                  float* __restrict__ pooled, int G) {
    __shared__ float red[8][32];
    int g = blockIdx.x;
    int t = threadIdx.x, c = t & 31, r = t >> 5;   // r in 0..7
    int s0 = gstart[g], s1 = gstart[g + 1];
    float acc = 0.f;
    for (int n = s0 + r; n < s1; n += 8) acc += out2[(size_t)n * 32 + c];
    red[r][c] = acc;
    __syncthreads();
    if (r == 0) {
        float s = red[0][c];
#pragma unroll
        for (int i = 1; i < 8; ++i) s += red[i][c];
        pooled[g * 32 + c] = s;
    }
}

// ---- final: out[g,cls] = (pooled[g]/cnt[g]) @ Wfc + bfc   (cnt from gstart diffs)
__global__ void k_final(const float* __restrict__ pooled, const int* __restrict__ gstart,
                        const float* __restrict__ Wfc, const float* __restrict__ bfc,
                        float* __restrict__ out) {
    int t = threadIdx.x;
    if (t >= 640) return;
    int g = t / 10, cls = t % 10;
    float rc = 1.f / fmaxf((float)(gstart[g + 1] - gstart[g]), 1.f);
    float acc = bfc[cls];
    for (int c = 0; c < 32; ++c) acc += pooled[g * 32 + c] * rc * Wfc[c * 10 + cls];
    out[g * 10 + cls] = acc;
}

extern "C" void kernel_launch(void* const* d_in, const int* in_sizes, int n_in,
                              void* d_out, int out_size, void* d_ws, size_t ws_size,
                              hipStream_t stream) {
    const float* x    = (const float*)d_in[0];
    const int*   ei   = (const int*)  d_in[1];
    const float* ea   = (const float*)d_in[2];
    const int*   batch= (const int*)  d_in[3];
    const float* W1   = (const float*)d_in[4];
    const float* as1  = (const float*)d_in[5];
    const float* ad1  = (const float*)d_in[6];
    const float* We1  = (const float*)d_in[7];
    const float* ae1  = (const float*)d_in[8];
    const float* b1   = (const float*)d_in[9];
    const float* W2   = (const float*)d_in[10];
    const float* as2  = (const float*)d_in[11];
    const float* ad2  = (const float*)d_in[12];
    const float* We2  = (const float*)d_in[13];
    const float* ae2  = (const float*)d_in[14];
    const float* b2   = (const float*)d_in[15];
    const float* Wfc  = (const float*)d_in[16];
    const float* bfc  = (const float*)d_in[17];
    float* out = (float*)d_out;

    const int N  = in_sizes[3];       // 50000
    const int E  = in_sizes[1] / 2;   // 1600000
    const int G  = 64;

    char* w = (char*)d_ws;
    size_t off = 0;
    auto alloc = [&](size_t bytes) -> void* {
        void* p = w + off;
        off = (off + bytes + 255) & ~(size_t)255;
        return p;
    };
    int*    deg      = (int*)   alloc((size_t)N * 4);
    int*    offsets  = (int*)   alloc((size_t)(N + 1) * 4);
    int*    cursor   = (int*)   alloc((size_t)N * 4);
    int*    csr_src  = (int*)   alloc((size_t)E * 4);
    float*  ale1_csr = (float*) alloc((size_t)E * 4 * 4);   // becomes alpha1 in place
    float*  ale2_csr = (float*) alloc((size_t)E * 4 * 4);   // becomes alpha2 in place
    float*  Mbuf     = (float*) alloc(128 * 4);
    __half* h16      = (__half*)alloc((size_t)N * 128 * 2); // h1 fp16; reused as h2
    float*  out1     = (float*) alloc((size_t)N * 128 * 4); // reused as out2
    float*  als      = (float*) alloc((size_t)N * 4 * 4);
    float*  ald      = (float*) alloc((size_t)N * 4 * 4);
    float*  rden     = (float*) alloc((size_t)N * 4 * 4);
    float*  selfa    = (float*) alloc((size_t)N * 4 * 4);
    int*    gstart   = (int*)   alloc((G + 1) * 4);
    float*  pooled   = (float*) alloc(G * 32 * 4);
    float*  out2 = out1;

    const int eb = (E + 255) / 256;
    const int nb4 = (N + 3) / 4;

    hipMemsetAsync(deg, 0, (size_t)N * 4, stream);

    k_prep<<<1, 128, 0, stream>>>(We1, ae1, We2, ae2, Mbuf);
    k_deg<<<eb, 256, 0, stream>>>(ei, deg, E);
    k_scan<<<1, 1024, 0, stream>>>(deg, offsets, cursor, N);
    k_fill_ale<<<eb, 256, 0, stream>>>(ei, ea, Mbuf, cursor, csr_src, ale1_csr, ale2_csr, E);
    k_gbound<<<1, 128, 0, stream>>>(batch, gstart, N, G);

    // ---------- layer 1 ----------
    k_gemm<128, 16><<<(N + 15) / 16, 256, 0, stream>>>(x, W1, h16, N);
    k_al<128><<<(N * 4 + 255) / 256, 256, 0, stream>>>(h16, as1, ad1, als, ald, N);
    k_alpha_node<<<nb4, 256, 0, stream>>>(ale1_csr, csr_src, als, ald, offsets, rden, selfa, N);
    k_aggf128<<<nb4, 256, 0, stream>>>(h16, ale1_csr, rden, selfa, offsets, csr_src, b1, out1, N);

    // ---------- layer 2 ----------
    k_gemm<32, 64><<<(N + 63) / 64, 256, 0, stream>>>(out1, W2, h16, N);
    k_al<32><<<(N * 4 + 255) / 256, 256, 0, stream>>>(h16, as2, ad2, als, ald, N);
    k_alpha_node<<<nb4, 256, 0, stream>>>(ale2_csr, csr_src, als, ald, offsets, rden, selfa, N);
    k_aggf32<<<nb4, 256, 0, stream>>>(h16, ale2_csr, rden, selfa, offsets, csr_src, b2, out2, N);

    // ---------- pool + fc ----------
    k_pool_grp<<<G, 256, 0, stream>>>(out2, gstart, pooled, G);
    k_final<<<1, 640, 0, stream>>>(pooled, gstart, Wfc, bfc, out);
}

// Round 5
// 553.759 us; speedup vs baseline: 6.2662x; 1.1207x over previous
//
#include <hip/hip_runtime.h>
#include <hip/hip_fp16.h>
#include <math.h>

typedef float4 f4;
#define NEG_SLOPE 0.2f

union h4pack { float2 f; __half2 h[2]; };

// ---- M[d][h] = sum_c We[d, h*C+c] * ae[h, c]   (M1: 16x4 from We1/ae1, M2 from We2/ae2)
__global__ void k_prep(const float* __restrict__ We1, const float* __restrict__ ae1,
                       const float* __restrict__ We2, const float* __restrict__ ae2,
                       float* __restrict__ M) {
    int t = threadIdx.x;                  // 128 threads
    if (t >= 128) return;
    int sel = t >> 6, i = t & 63, d = i >> 2, h = i & 3;
    const float* W  = sel ? We2 : We1;
    const float* ae = sel ? ae2 : ae1;
    int C = sel ? 8 : 32, ncol = sel ? 32 : 128;
    float s = 0.f;
    for (int c = 0; c < C; ++c) s += W[d * ncol + h * C + c] * ae[h * C + c];
    M[sel * 64 + d * 4 + h] = s;
}

// ---- deg[dst]++ per real edge (int atomics only)
__global__ void k_deg(const int* __restrict__ ei, int* __restrict__ deg, int E) {
    int e = blockIdx.x * 256 + threadIdx.x;
    if (e < E) atomicAdd(&deg[ei[E + e]], 1);
}

// ---- exclusive scan of deg -> offsets[0..N], cursor copy. One block of 1024.
__global__ void k_scan(const int* __restrict__ deg, int* __restrict__ offsets,
                       int* __restrict__ cursor, int N) {
    __shared__ int ts[1024];
    int t = threadIdx.x;
    int CH = (N + 1023) / 1024;
    int lo = t * CH, hi = min(lo + CH, N);
    int s = 0;
    for (int i = lo; i < hi; ++i) s += deg[i];
    ts[t] = s;
    __syncthreads();
    for (int off = 1; off < 1024; off <<= 1) {
        int v = (t >= off) ? ts[t - off] : 0;
        __syncthreads();
        ts[t] += v;
        __syncthreads();
    }
    int run = (t == 0) ? 0 : ts[t - 1];
    for (int i = lo; i < hi; ++i) { offsets[i] = run; cursor[i] = run; run += deg[i]; }
    if (t == 1023) offsets[N] = ts[1023];
}

// ---- fill CSR (by dst): src node + fp16 al_e for BOTH layers, in CSR slot order
__global__ void k_fill_ale(const int* __restrict__ ei, const float* __restrict__ ea,
                           const float* __restrict__ Mbuf, int* __restrict__ cursor,
                           int* __restrict__ csr_src,
                           __half* __restrict__ ale1_16, __half* __restrict__ ale2_16,
                           int E) {
    __shared__ float Ms[128];
    if (threadIdx.x < 128) Ms[threadIdx.x] = Mbuf[threadIdx.x];
    __syncthreads();
    int e = blockIdx.x * 256 + threadIdx.x;
    if (e >= E) return;
    int sr = ei[e], d = ei[E + e];
    const f4* row = (const f4*)(ea + (size_t)e * 16);
    f4 r0 = row[0], r1 = row[1], r2 = row[2], r3 = row[3];
    float a[16] = { r0.x, r0.y, r0.z, r0.w, r1.x, r1.y, r1.z, r1.w,
                    r2.x, r2.y, r2.z, r2.w, r3.x, r3.y, r3.z, r3.w };
    float s10 = 0.f, s11 = 0.f, s12 = 0.f, s13 = 0.f;
    float s20 = 0.f, s21 = 0.f, s22 = 0.f, s23 = 0.f;
#pragma unroll
    for (int dd = 0; dd < 16; ++dd) {
        float av = a[dd];
        s10 += av * Ms[dd * 4 + 0]; s11 += av * Ms[dd * 4 + 1];
        s12 += av * Ms[dd * 4 + 2]; s13 += av * Ms[dd * 4 + 3];
        s20 += av * Ms[64 + dd * 4 + 0]; s21 += av * Ms[64 + dd * 4 + 1];
        s22 += av * Ms[64 + dd * 4 + 2]; s23 += av * Ms[64 + dd * 4 + 3];
    }
    int slot = atomicAdd(&cursor[d], 1);
    csr_src[slot] = sr;
    h4pack p1, p2;
    p1.h[0] = __floats2half2_rn(s10, s11); p1.h[1] = __floats2half2_rn(s12, s13);
    p2.h[0] = __floats2half2_rn(s20, s21); p2.h[1] = __floats2half2_rn(s22, s23);
    ((float2*)ale1_16)[slot] = p1.f;
    ((float2*)ale2_16)[slot] = p2.f;
}

// ---- LDS-tiled fp32 GEMM, fp16 output: Hout[N,NOUT] = half(X[N,128] @ W[128,NOUT])
template<int NOUT, int ROWS>
__global__ __launch_bounds__(256) void k_gemm(const float* __restrict__ X,
                                              const float* __restrict__ W,
                                              __half* __restrict__ Hout, int N) {
    __shared__ __align__(16) float xs[ROWS][128];
    int row0 = blockIdx.x * ROWS;
    int tid = threadIdx.x;
    constexpr int NF4 = ROWS * 32;
    const f4* x4 = (const f4*)X;
    for (int i = tid; i < NF4; i += 256) {
        int r = i >> 5, k4 = i & 31;
        f4 v;
        if (row0 + r < N) v = x4[(size_t)(row0 + r) * 32 + k4];
        else { v.x = v.y = v.z = v.w = 0.f; }
        ((f4*)&xs[r][0])[k4] = v;
    }
    __syncthreads();
    constexpr int GRP = 256 / NOUT;
    constexpr int PR  = ROWS / GRP;
    int col = tid % NOUT, rg = tid / NOUT;
    float acc[PR];
#pragma unroll
    for (int r = 0; r < PR; ++r) acc[r] = 0.f;
    for (int k = 0; k < 128; ++k) {
        float w = W[k * NOUT + col];
#pragma unroll
        for (int r = 0; r < PR; ++r) acc[r] += xs[rg + r * GRP][k] * w;
    }
#pragma unroll
    for (int r = 0; r < PR; ++r) {
        int row = row0 + rg + r * GRP;
        if (row < N) Hout[(size_t)row * NOUT + col] = __float2half(acc[r]);
    }
}

// ---- per (node, head): al_src/al_dst from fp16 h
template<int C>
__global__ void k_al(const __half* __restrict__ Hm, const float* __restrict__ as_,
                     const float* __restrict__ ad_, float* __restrict__ als,
                     float* __restrict__ ald, int N) {
    int idx = blockIdx.x * 256 + threadIdx.x;
    int n = idx >> 2, h = idx & 3;
    if (n >= N) return;
    constexpr int CH = C / 4;
    const __half2* h2p = (const __half2*)(Hm + (size_t)n * C + h * CH);
    float a = 0.f, b = 0.f;
#pragma unroll
    for (int c = 0; c < CH / 2; ++c) {
        float2 v = __half22float2(h2p[c]);
        a += v.x * as_[h * CH + 2 * c] + v.y * as_[h * CH + 2 * c + 1];
        b += v.x * ad_[h * CH + 2 * c] + v.y * ad_[h * CH + 2 * c + 1];
    }
    als[n * 4 + h] = a;
    ald[n * 4 + h] = b;
}

// ---- wave-per-node: alpha16[s][h] = exp(leaky(als[src]+ald[n]+ale16[s][h])) (in place),
//      emit rden[n][h] = 1/(sum_exp + e_self + 1e-16), selfa[n][h] = e_self
__global__ __launch_bounds__(256) void k_alpha_node(__half* __restrict__ ale16,
                                                    const int* __restrict__ csr_src,
                                                    const float* __restrict__ als,
                                                    const float* __restrict__ ald,
                                                    const int* __restrict__ offsets,
                                                    float* __restrict__ rden,
                                                    float* __restrict__ selfa, int N) {
    int n = (blockIdx.x * 256 + threadIdx.x) >> 6;
    int lane = threadIdx.x & 63;
    if (n >= N) return;
    int j = lane >> 2, h = lane & 3;   // 16 edges x 4 heads per iteration
    int s0 = offsets[n], s1 = offsets[n + 1];
    float aldn = ald[n * 4 + h];
    float den = 0.f, asum = 0.f;
    for (int base = s0; base < s1; base += 16) {
        int s = base + j;
        if (s < s1) {
            int src = csr_src[s];
            float ale = __half2float(ale16[s * 4 + h]);
            float v = als[src * 4 + h] + aldn + ale;
            v = (v > 0.f) ? v : NEG_SLOPE * v;
            float e = __expf(v);
            ale16[s * 4 + h] = __float2half(e);
            den += e; asum += ale;
        }
    }
    den  += __shfl_xor(den, 4);  den  += __shfl_xor(den, 8);
    den  += __shfl_xor(den, 16); den  += __shfl_xor(den, 32);
    asum += __shfl_xor(asum, 4);  asum += __shfl_xor(asum, 8);
    asum += __shfl_xor(asum, 16); asum += __shfl_xor(asum, 32);
    if (j == 0) {
        float rdeg = 1.f / fmaxf((float)(s1 - s0), 1.f);
        float v = als[n * 4 + h] + aldn + asum * rdeg;
        v = (v > 0.f) ? v : NEG_SLOPE * v;
        float es = __expf(v);
        selfa[n * 4 + h] = es;
        rden[n * 4 + h] = 1.f / (den + es + 1e-16f);
    }
}

// ---- layer-1 aggregation: gather-FMA, wave-per-node, unroll x4, predicated tail
__global__ __launch_bounds__(256) void k_aggf128(const __half* __restrict__ h16,
                                                 const __half* __restrict__ alpha16,
                                                 const float* __restrict__ rden,
                                                 const float* __restrict__ selfa,
                                                 const int* __restrict__ offsets,
                                                 const int* __restrict__ csr_src,
                                                 const float* __restrict__ bias,
                                                 float* __restrict__ Out, int N) {
    int n = (blockIdx.x * 256 + threadIdx.x) >> 6;
    int lane = threadIdx.x & 63;
    if (n >= N) return;
    int hd = lane >> 4;                 // head of channels 2l, 2l+1
    int s0 = offsets[n], s1 = offsets[n + 1];
    const __half2* H2 = (const __half2*)h16;
    float acc0 = 0.f, acc1 = 0.f;
    int e1 = s1 - 1;
    for (int s = s0; s < s1; s += 4) {
        int sA = s;
        int sB = min(s + 1, e1), sC = min(s + 2, e1), sD = min(s + 3, e1);
        int srcA = csr_src[sA], srcB = csr_src[sB], srcC = csr_src[sC], srcD = csr_src[sD];
        float aA = __half2float(alpha16[sA * 4 + hd]);
        float aB = (s + 1 <= e1) ? __half2float(alpha16[sB * 4 + hd]) : 0.f;
        float aC = (s + 2 <= e1) ? __half2float(alpha16[sC * 4 + hd]) : 0.f;
        float aD = (s + 3 <= e1) ? __half2float(alpha16[sD * 4 + hd]) : 0.f;
        __half2 hA = H2[(size_t)srcA * 64 + lane];
        __half2 hB = H2[(size_t)srcB * 64 + lane];
        __half2 hC = H2[(size_t)srcC * 64 + lane];
        __half2 hD = H2[(size_t)srcD * 64 + lane];
        float2 fA = __half22float2(hA), fB = __half22float2(hB);
        float2 fC = __half22float2(hC), fD = __half22float2(hD);
        acc0 = fmaf(aA, fA.x, acc0); acc1 = fmaf(aA, fA.y, acc1);
        acc0 = fmaf(aB, fB.x, acc0); acc1 = fmaf(aB, fB.y, acc1);
        acc0 = fmaf(aC, fC.x, acc0); acc1 = fmaf(aC, fC.y, acc1);
        acc0 = fmaf(aD, fD.x, acc0); acc1 = fmaf(aD, fD.y, acc1);
    }
    float sa = selfa[n * 4 + hd];
    float2 hn = __half22float2(H2[(size_t)n * 64 + lane]);
    acc0 = fmaf(sa, hn.x, acc0);
    acc1 = fmaf(sa, hn.y, acc1);
    float rd = rden[n * 4 + hd];
    float2 bv = ((const float2*)bias)[lane];
    float2 o;
    o.x = fmaxf(fmaf(acc0, rd, bv.x), 0.f);
    o.y = fmaxf(fmaf(acc1, rd, bv.y), 0.f);
    ((float2*)Out)[(size_t)n * 64 + lane] = o;
}

// ---- layer-2 aggregation: 4 edges/iter across the wave, unroll x2 (8 gathers in flight)
__global__ __launch_bounds__(256) void k_aggf32(const __half* __restrict__ h16,
                                                const __half* __restrict__ alpha16,
                                                const float* __restrict__ rden,
                                                const float* __restrict__ selfa,
                                                const int* __restrict__ offsets,
                                                const int* __restrict__ csr_src,
                                                const float* __restrict__ bias,
                                                float* __restrict__ Out, int N) {
    int n = (blockIdx.x * 256 + threadIdx.x) >> 6;
    int lane = threadIdx.x & 63;
    if (n >= N) return;
    int j = lane >> 4;                  // edge sub-slot 0..3
    int p = lane & 15;                  // half2 index -> channels 2p,2p+1
    int hd = p >> 2;                    // head
    int s0 = offsets[n], s1 = offsets[n + 1];
    const __half2* H2 = (const __half2*)h16;
    float acc0 = 0.f, acc1 = 0.f;
    int e1 = s1 - 1;
    for (int s = s0 + j; s < s1; s += 8) {
        int sA = s;
        int sB = min(s + 4, e1);
        int srcA = csr_src[sA], srcB = csr_src[sB];
        float aA = __half2float(alpha16[sA * 4 + hd]);
        float aB = (s + 4 <= e1) ? __half2float(alpha16[sB * 4 + hd]) : 0.f;
        __half2 hA = H2[(size_t)srcA * 16 + p];
        __half2 hB = H2[(size_t)srcB * 16 + p];
        float2 fA = __half22float2(hA), fB = __half22float2(hB);
        acc0 = fmaf(aA, fA.x, acc0); acc1 = fmaf(aA, fA.y, acc1);
        acc0 = fmaf(aB, fB.x, acc0); acc1 = fmaf(aB, fB.y, acc1);
    }
    acc0 += __shfl_xor(acc0, 16); acc0 += __shfl_xor(acc0, 32);
    acc1 += __shfl_xor(acc1, 16); acc1 += __shfl_xor(acc1, 32);
    if (j == 0) {
        float sa = selfa[n * 4 + hd];
        float2 hn = __half22float2(H2[(size_t)n * 16 + p]);
        acc0 = fmaf(sa, hn.x, acc0);
        acc1 = fmaf(sa, hn.y, acc1);
        float rd = rden[n * 4 + hd];
        float2 bv = ((const float2*)bias)[p];
        float2 o;
        o.x = fmaxf(fmaf(acc0, rd, bv.x), 0.f);
        o.y = fmaxf(fmaf(acc1, rd, bv.y), 0.f);
        ((float2*)Out)[(size_t)n * 16 + p] = o;
    }
}

// ---- group boundaries: gstart[g] = lower_bound(batch, g), g in [0,64]
__global__ void k_gbound(const int* __restrict__ batch, int* __restrict__ gstart, int N, int G) {
    int g = threadIdx.x;
    if (g > G) return;
    int lo = 0, hi = N;
    while (lo < hi) {
        int mid = (lo + hi) >> 1;
        if (batch[mid] < g) lo = mid + 1; else hi = mid;
    }
    gstart[g] = lo;
}

// ---- atomic-free mean pool: one block per group, contiguous slab reduce
__global__ __launch_bounds__(256) void k_pool_grp(const float* __restrict__ out2,
                                                  const int* __restrict__ gstart,
                                                  float* __restrict__ pooled, int G) {
    __shared__ float red[8][32];
    int g = blockIdx.x;
    int t = threadIdx.x, c = t & 31, r = t >> 5;   // r in 0..7
    int s0 = gstart[g], s1 = gstart[g + 1];
    float acc = 0.f;
    for (int n = s0 + r; n < s1; n += 8) acc += out2[(size_t)n * 32 + c];
    red[r][c] = acc;
    __syncthreads();
    if (r == 0) {
        float s = red[0][c];
#pragma unroll
        for (int i = 1; i < 8; ++i) s += red[i][c];
        pooled[g * 32 + c] = s;
    }
}

// ---- final: out[g,cls] = (pooled[g]/cnt[g]) @ Wfc + bfc   (cnt from gstart diffs)
__global__ void k_final(const float* __restrict__ pooled, const int* __restrict__ gstart,
                        const float* __restrict__ Wfc, const float* __restrict__ bfc,
                        float* __restrict__ out) {
    int t = threadIdx.x;
    if (t >= 640) return;
    int g = t / 10, cls = t % 10;
    float rc = 1.f / fmaxf((float)(gstart[g + 1] - gstart[g]), 1.f);
    float acc = bfc[cls];
    for (int c = 0; c < 32; ++c) acc += pooled[g * 32 + c] * rc * Wfc[c * 10 + cls];
    out[g * 10 + cls] = acc;
}

extern "C" void kernel_launch(void* const* d_in, const int* in_sizes, int n_in,
                              void* d_out, int out_size, void* d_ws, size_t ws_size,
                              hipStream_t stream) {
    const float* x    = (const float*)d_in[0];
    const int*   ei   = (const int*)  d_in[1];
    const float* ea   = (const float*)d_in[2];
    const int*   batch= (const int*)  d_in[3];
    const float* W1   = (const float*)d_in[4];
    const float* as1  = (const float*)d_in[5];
    const float* ad1  = (const float*)d_in[6];
    const float* We1  = (const float*)d_in[7];
    const float* ae1  = (const float*)d_in[8];
    const float* b1   = (const float*)d_in[9];
    const float* W2   = (const float*)d_in[10];
    const float* as2  = (const float*)d_in[11];
    const float* ad2  = (const float*)d_in[12];
    const float* We2  = (const float*)d_in[13];
    const float* ae2  = (const float*)d_in[14];
    const float* b2   = (const float*)d_in[15];
    const float* Wfc  = (const float*)d_in[16];
    const float* bfc  = (const float*)d_in[17];
    float* out = (float*)d_out;

    const int N  = in_sizes[3];       // 50000
    const int E  = in_sizes[1] / 2;   // 1600000
    const int G  = 64;

    char* w = (char*)d_ws;
    size_t off = 0;
    auto alloc = [&](size_t bytes) -> void* {
        void* p = w + off;
        off = (off + bytes + 255) & ~(size_t)255;
        return p;
    };
    int*    deg      = (int*)   alloc((size_t)N * 4);
    int*    offsets  = (int*)   alloc((size_t)(N + 1) * 4);
    int*    cursor   = (int*)   alloc((size_t)N * 4);
    int*    csr_src  = (int*)   alloc((size_t)E * 4);
    __half* ale1_16  = (__half*)alloc((size_t)E * 4 * 2);   // becomes alpha1 in place
    __half* ale2_16  = (__half*)alloc((size_t)E * 4 * 2);   // becomes alpha2 in place
    float*  Mbuf     = (float*) alloc(128 * 4);
    __half* h16      = (__half*)alloc((size_t)N * 128 * 2); // h1 fp16; reused as h2
    float*  out1     = (float*) alloc((size_t)N * 128 * 4); // reused as out2
    float*  als      = (float*) alloc((size_t)N * 4 * 4);
    float*  ald      = (float*) alloc((size_t)N * 4 * 4);
    float*  rden     = (float*) alloc((size_t)N * 4 * 4);
    float*  selfa    = (float*) alloc((size_t)N * 4 * 4);
    int*    gstart   = (int*)   alloc((G + 1) * 4);
    float*  pooled   = (float*) alloc(G * 32 * 4);
    float*  out2 = out1;

    const int eb = (E + 255) / 256;
    const int nb4 = (N + 3) / 4;

    hipMemsetAsync(deg, 0, (size_t)N * 4, stream);

    k_prep<<<1, 128, 0, stream>>>(We1, ae1, We2, ae2, Mbuf);
    k_deg<<<eb, 256, 0, stream>>>(ei, deg, E);
    k_scan<<<1, 1024, 0, stream>>>(deg, offsets, cursor, N);
    k_fill_ale<<<eb, 256, 0, stream>>>(ei, ea, Mbuf, cursor, csr_src, ale1_16, ale2_16, E);
    k_gbound<<<1, 128, 0, stream>>>(batch, gstart, N, G);

    // ---------- layer 1 ----------
    k_gemm<128, 16><<<(N + 15) / 16, 256, 0, stream>>>(x, W1, h16, N);
    k_al<128><<<(N * 4 + 255) / 256, 256, 0, stream>>>(h16, as1, ad1, als, ald, N);
    k_alpha_node<<<nb4, 256, 0, stream>>>(ale1_16, csr_src, als, ald, offsets, rden, selfa, N);
    k_aggf128<<<nb4, 256, 0, stream>>>(h16, ale1_16, rden, selfa, offsets, csr_src, b1, out1, N);

    // ---------- layer 2 ----------
    k_gemm<32, 64><<<(N + 63) / 64, 256, 0, stream>>>(out1, W2, h16, N);
    k_al<32><<<(N * 4 + 255) / 256, 256, 0, stream>>>(h16, as2, ad2, als, ald, N);
    k_alpha_node<<<nb4, 256, 0, stream>>>(ale2_16, csr_src, als, ald, offsets, rden, selfa, N);
    k_aggf32<<<nb4, 256, 0, stream>>>(h16, ale2_16, rden, selfa, offsets, csr_src, b2, out2, N);

    // ---------- pool + fc ----------
    k_pool_grp<<<G, 256, 0, stream>>>(out2, gstart, pooled, G);
    k_final<<<1, 640, 0, stream>>>(pooled, gstart, Wfc, bfc, out);
}